// Round 2
// baseline (247.993 us; speedup 1.0000x reference)
//
#include <hip/hip_runtime.h>
#include <hip/hip_bf16.h>

// out[b, s, d] = in[b, s, d] + pe[s, d]
// pe[s, 2p]   = sin(s / 10000^(2p/1024)),  pe[s, 2p+1] = cos(...)
//
// One thread per float4 of the (S, D) plane, looping the 8-image batch.
// R1 post-mortem: compiler serialized the fused load/add/store loop
// (VGPR=28 -> ~1 outstanding load/wave -> 2.1 TB/s, latency-bound).
// Fix: issue all 8 independent loads first (explicit v[8]), compute trig
// while they are in flight, then add + NON-TEMPORAL store (output is
// write-once; keep it from evicting the L3-resident input).

#define SEQ_LEN 4096
#define D_MODEL 1024

using f32x4 = __attribute__((ext_vector_type(4))) float;

__global__ void __launch_bounds__(256)
pe_add_kernel(const float* __restrict__ in, float* __restrict__ out) {
    constexpr int D4     = D_MODEL / 4;          // float4s per row = 256
    constexpr int PLANE4 = SEQ_LEN * D4;         // float4s per image

    int idx = blockIdx.x * blockDim.x + threadIdx.x;   // 0 .. PLANE4-1
    int d4  = idx & (D4 - 1);
    int s   = idx >> 8;                                // D4 == 2^8

    const f32x4* src = reinterpret_cast<const f32x4*>(in)  + idx;
    f32x4*       dst = reinterpret_cast<f32x4*>      (out) + idx;

    // Issue all 8 batch loads back-to-back: 8-deep MLP per wave.
    f32x4 v[8];
    #pragma unroll
    for (int b = 0; b < 8; ++b)
        v[b] = src[b * PLANE4];

    // Trig computes while the loads are in flight.
    // angle(p) = s * 10000^(-2p/1024) = s * exp2(-p * (2/1024)*log2(10000))
    constexpr float K = -0.025952563241307517f;
    float sf   = (float)s;
    int   p0   = d4 * 2;
    float ang0 = sf * exp2f((float)p0 * K);
    float ang1 = sf * exp2f((float)(p0 + 1) * K);
    float s0, c0, s1, c1;
    sincosf(ang0, &s0, &c0);
    sincosf(ang1, &s1, &c1);

    #pragma unroll
    for (int b = 0; b < 8; ++b) {
        f32x4 t = v[b];
        t.x += s0; t.y += c0; t.z += s1; t.w += c1;
        __builtin_nontemporal_store(t, dst + b * PLANE4);
    }
}

extern "C" void kernel_launch(void* const* d_in, const int* in_sizes, int n_in,
                              void* d_out, int out_size, void* d_ws, size_t ws_size,
                              hipStream_t stream) {
    const float* in  = (const float*)d_in[0];
    float*       out = (float*)d_out;

    constexpr int THREADS = SEQ_LEN * (D_MODEL / 4); // 1,048,576
    dim3 block(256);
    dim3 grid(THREADS / 256);                        // 4096 blocks
    pe_add_kernel<<<grid, block, 0, stream>>>(in, out);
}

// Round 3
// 221.104 us; speedup vs baseline: 1.1216x; 1.1216x over previous
//
#include <hip/hip_runtime.h>
#include <hip/hip_bf16.h>

// out[b, s, d] = in[b, s, d] + pe[s, d]
// pe[s, 2p]   = sin(s / 10000^(2p/1024)),  pe[s, 2p+1] = cos(...)
//
// R2 post-mortem: per-thread batch ILP was defeated by the compiler twice
// (VGPR pinned at 28, serialized round-trips, 2.0 TB/s). Switch to the
// m13-proven pure-TLP copy pattern: one thread per float4 of the FULL
// [8, S, D] tensor, single load -> add -> store. 8.4M threads / 32768
// blocks give the memory system maximum outstanding requests via wave
// count instead of per-thread ILP. Trig recomputed per thread (~50 cyc/CU
// per wave VALU vs ~200 cyc/CU memory budget -> still memory-bound).

#define SEQ_LEN 4096
#define D_MODEL 1024

using f32x4 = __attribute__((ext_vector_type(4))) float;

__global__ void __launch_bounds__(256)
pe_add_kernel(const float* __restrict__ in, float* __restrict__ out) {
    constexpr int D4 = D_MODEL / 4;                    // float4s per row = 256

    int idx = blockIdx.x * blockDim.x + threadIdx.x;   // 0 .. 8*S*D4-1

    // Issue the load FIRST; trig fills its shadow.
    const f32x4* src = reinterpret_cast<const f32x4*>(in)  + idx;
    f32x4 v = *src;

    int d4 = idx & (D4 - 1);                           // float4 within row
    int s  = (idx >> 8) & (SEQ_LEN - 1);               // row within image

    // angle(p) = s * 10000^(-2p/1024) = s * exp2(-p * (2/1024)*log2(10000))
    constexpr float K = -0.025952563241307517f;
    float sf   = (float)s;
    int   p0   = d4 * 2;
    float ang0 = sf * exp2f((float)p0 * K);
    float ang1 = sf * exp2f((float)(p0 + 1) * K);
    float s0, c0, s1, c1;
    sincosf(ang0, &s0, &c0);
    sincosf(ang1, &s1, &c1);

    v.x += s0; v.y += c0; v.z += s1; v.w += c1;
    __builtin_nontemporal_store(v, reinterpret_cast<f32x4*>(out) + idx);
}

extern "C" void kernel_launch(void* const* d_in, const int* in_sizes, int n_in,
                              void* d_out, int out_size, void* d_ws, size_t ws_size,
                              hipStream_t stream) {
    const float* in  = (const float*)d_in[0];
    float*       out = (float*)d_out;

    int total4 = in_sizes[0] / 4;                      // 8,388,608 float4s
    dim3 block(256);
    dim3 grid(total4 / 256);                           // 32768 blocks
    pe_add_kernel<<<grid, block, 0, stream>>>(in, out);
}